// Round 1
// baseline (364.826 us; speedup 1.0000x reference)
//
#include <hip/hip_runtime.h>
#include <hip/hip_bf16.h>

// Shapes: bz=32, rv_num=10, rv_len=128, in_feat=300, out_feat=128
// N = 320 reviews, tokens per side = 40960, M = 1280 tokens/sample.

#define K_FEAT 300
#define H 128
#define TM 64
#define KC 60
#define NTOK 40960          // tokens per side
#define NREV 320            // reviews per side
#define TOK_PER_SAMPLE 1280

// ---------------- Kernel 1: FC + ReLU (fp32 vector GEMM) ----------------
// grid.x = 1280 (640 blocks side a, 640 side b); block = 256
__global__ __launch_bounds__(256, 3) void fc_relu_kernel(
    const float* __restrict__ seq_a, const float* __restrict__ seq_b,
    const float* __restrict__ W, const float* __restrict__ bias,
    float* __restrict__ ta, float* __restrict__ tb)
{
    __shared__ float A_s[TM * KC];     // [token][k] row-major
    __shared__ float W_s[KC * H];      // [k][h] row-major

    int blk = blockIdx.x;
    const float* seq;
    float* outp;
    if (blk < 640) { seq = seq_a; outp = ta; }
    else           { seq = seq_b; outp = tb; blk -= 640; }

    const int tid = threadIdx.x;
    const int tok0 = blk * TM;
    const int fx = tid & 31;   // feature group: h = fx*4 .. fx*4+3
    const int ty = tid >> 5;   // token group: tokens ty*8 .. ty*8+7

    float acc[8][4];
#pragma unroll
    for (int r = 0; r < 8; ++r)
#pragma unroll
        for (int c = 0; c < 4; ++c) acc[r][c] = 0.f;

    for (int k0 = 0; k0 < K_FEAT; k0 += KC) {
        // Stage A tile: 64 tokens x KC(=60) floats, as float4 (60/4 = 15 per token)
        for (int i4 = tid; i4 < TM * (KC / 4); i4 += 256) {
            int t = i4 / (KC / 4);
            int k4 = i4 - t * (KC / 4);
            float4 v = *(const float4*)&seq[(size_t)(tok0 + t) * K_FEAT + k0 + k4 * 4];
            *(float4*)&A_s[t * KC + k4 * 4] = v;
        }
        // Stage W tile: KC x 128 floats, as float4 (32 float4 per k-row)
        for (int i4 = tid; i4 < KC * (H / 4); i4 += 256) {
            int k = i4 >> 5;
            int h4 = i4 & 31;
            float4 v = *(const float4*)&W[(size_t)(k0 + k) * H + h4 * 4];
            *(float4*)&W_s[k * H + h4 * 4] = v;
        }
        __syncthreads();

#pragma unroll 4
        for (int k = 0; k < KC; ++k) {
            float4 w = *(const float4*)&W_s[k * H + fx * 4];
            float a[8];
#pragma unroll
            for (int r = 0; r < 8; ++r) a[r] = A_s[(ty * 8 + r) * KC + k];
#pragma unroll
            for (int r = 0; r < 8; ++r) {
                acc[r][0] = fmaf(a[r], w.x, acc[r][0]);
                acc[r][1] = fmaf(a[r], w.y, acc[r][1]);
                acc[r][2] = fmaf(a[r], w.z, acc[r][2]);
                acc[r][3] = fmaf(a[r], w.w, acc[r][3]);
            }
        }
        __syncthreads();
    }

    // Epilogue: + bias, ReLU, store
    float4 bb = *(const float4*)&bias[fx * 4];
#pragma unroll
    for (int r = 0; r < 8; ++r) {
        int tok = tok0 + ty * 8 + r;
        float4 v;
        v.x = fmaxf(acc[r][0] + bb.x, 0.f);
        v.y = fmaxf(acc[r][1] + bb.y, 0.f);
        v.z = fmaxf(acc[r][2] + bb.z, 0.f);
        v.w = fmaxf(acc[r][3] + bb.w, 0.f);
        *(float4*)&outp[(size_t)tok * H + fx * 4] = v;
    }
}

// ---------------- Kernel 2: per-sample feature means ----------------
// grid.x = 64 (32 samples x 2 sides); block = 256
__global__ void mean_kernel(const float* __restrict__ ta, const float* __restrict__ tb,
                            float* __restrict__ mean_a, float* __restrict__ mean_b)
{
    int b = blockIdx.x & 31;
    int side = blockIdx.x >> 5;
    const float* t = side ? tb : ta;
    float* m = side ? mean_b : mean_a;

    int tid = threadIdx.x;
    int d = tid & 127;
    int g = tid >> 7;           // 0 or 1
    const float* base = t + (size_t)b * TOK_PER_SAMPLE * H;

    float s = 0.f;
    for (int tok = g; tok < TOK_PER_SAMPLE; tok += 2)
        s += base[(size_t)tok * H + d];

    __shared__ float red[256];
    red[tid] = s;
    __syncthreads();
    if (tid < 128)
        m[b * H + d] = (red[tid] + red[tid + 128]) * (1.0f / (float)TOK_PER_SAMPLE);
}

// ---------------- Kernel 3: scores -> masked softmax -> weighted sum ----------------
// grid.x = 640 (320 reviews x 2 sides); block = 128 (one thread per token / feature)
__global__ void attn_kernel(
    const float* __restrict__ ta, const float* __restrict__ tb,
    const int* __restrict__ mask_a, const int* __restrict__ mask_b,
    const float* __restrict__ mean_a, const float* __restrict__ mean_b,
    float* __restrict__ out)
{
    int n = blockIdx.x;
    int side = 0;
    if (n >= NREV) { side = 1; n -= NREV; }

    const float* t = side ? tb : ta;
    const int* mask = side ? mask_b : mask_a;
    const float* mean_o = side ? mean_a : mean_b;  // mean of the OTHER side
    float* out_vec = out + (side ? NREV * H : 0);              // a_out / b_out
    float* out_w = out + 2 * NREV * H + (side ? NREV * H : 0); // atob_w / btoa_w

    int sample = n / 10;
    int l = threadIdx.x;  // 0..127

    __shared__ float tile[128 * 129];  // pad +1: row reads 2-way (free), col reads conflict-free
    __shared__ float mean_s[128];
    __shared__ float w_s[128];
    __shared__ float red[2];

    const float* rowbase = t + (size_t)n * 128 * H;
    for (int i = l; i < 128 * H; i += 128) {
        int r = i >> 7, d = i & 127;
        tile[r * 129 + d] = rowbase[i];
    }
    mean_s[l] = mean_o[sample * H + l];
    __syncthreads();

    // score_l = dot(row l, mean_other)   (mean already includes 1/1280)
    float s = 0.f;
    const float* myrow = &tile[l * 129];
#pragma unroll 8
    for (int j = 0; j < 128; ++j) s = fmaf(myrow[j], mean_s[j], s);

    int mv = mask[n * 128 + l];
    float logit = (mv > 0) ? s : -1e9f;

    // max over 128 threads (2 waves)
    float mx = logit;
    for (int off = 32; off > 0; off >>= 1) mx = fmaxf(mx, __shfl_xor(mx, off));
    if ((l & 63) == 0) red[l >> 6] = mx;
    __syncthreads();
    mx = fmaxf(red[0], red[1]);
    __syncthreads();  // red reused below

    float e = __expf(logit - mx);  // masked lanes: exp(~-1e9) -> 0
    float ssum = e;
    for (int off = 32; off > 0; off >>= 1) ssum += __shfl_xor(ssum, off);
    if ((l & 63) == 0) red[l >> 6] = ssum;
    __syncthreads();
    ssum = red[0] + red[1];

    float w = e / ssum;
    w_s[l] = w;
    out_w[n * 128 + l] = w;
    __syncthreads();

    // out[d] = sum_l w_l * tile[l][d]   (thread = feature d; column reads conflict-free)
    int d = l;
    float o = 0.f;
#pragma unroll 8
    for (int ll = 0; ll < 128; ++ll) o = fmaf(w_s[ll], tile[ll * 129 + d], o);
    out_vec[n * 128 + d] = o;
}

// ---------------- Launch ----------------
extern "C" void kernel_launch(void* const* d_in, const int* in_sizes, int n_in,
                              void* d_out, int out_size, void* d_ws, size_t ws_size,
                              hipStream_t stream)
{
    const float* seq_a = (const float*)d_in[0];
    const float* seq_b = (const float*)d_in[1];
    const int* mask_a = (const int*)d_in[2];
    const int* mask_b = (const int*)d_in[3];
    const float* W = (const float*)d_in[4];
    const float* bias = (const float*)d_in[5];
    float* out = (float*)d_out;

    float* ws = (float*)d_ws;
    float* ta = ws;                          // 40960*128
    float* tb = ta + (size_t)NTOK * H;       // 40960*128
    float* mean_a = tb + (size_t)NTOK * H;   // 32*128
    float* mean_b = mean_a + 32 * H;         // 32*128

    fc_relu_kernel<<<1280, 256, 0, stream>>>(seq_a, seq_b, W, bias, ta, tb);
    mean_kernel<<<64, 256, 0, stream>>>(ta, tb, mean_a, mean_b);
    attn_kernel<<<640, 128, 0, stream>>>(ta, tb, mask_a, mask_b, mean_a, mean_b, out);
}

// Round 2
// 221.562 us; speedup vs baseline: 1.6466x; 1.6466x over previous
//
#include <hip/hip_runtime.h>
#include <hip/hip_bf16.h>

// Shapes: bz=32, rv_num=10, rv_len=128, in_feat=300, out_feat=128
// N = 320 reviews, tokens per side = 40960, M = 1280 tokens/sample.

#define K_FEAT 300
#define H 128
#define TM 64
#define KC 60
#define NTOK 40960          // tokens per side
#define NREV 320            // reviews per side
#define TOK_PER_SAMPLE 1280

// ---------------- Kernel 0: zero the mean accumulators ----------------
__global__ void zero_kernel(float* __restrict__ p, int n)
{
    int i = blockIdx.x * blockDim.x + threadIdx.x;
    if (i < n) p[i] = 0.f;
}

// ---------------- Kernel 1: FC + ReLU (fp32 vector GEMM) + fused mean accumulation ----------------
// grid.x = 1280 (640 blocks side a, 640 side b); block = 256
// Each block covers 64 tokens, all within ONE sample (1280/64 = 20 blocks/sample).
__global__ __launch_bounds__(256, 3) void fc_relu_kernel(
    const float* __restrict__ seq_a, const float* __restrict__ seq_b,
    const float* __restrict__ W, const float* __restrict__ bias,
    float* __restrict__ ta, float* __restrict__ tb,
    float* __restrict__ msum_a, float* __restrict__ msum_b)
{
    __shared__ float A_s[TM * KC];     // [token][k] row-major
    __shared__ float W_s[KC * H];      // [k][h] row-major
    __shared__ float msum_s[H];        // block-local feature sums (post-ReLU)

    int blk = blockIdx.x;
    const float* seq;
    float* outp;
    float* msum;
    if (blk < 640) { seq = seq_a; outp = ta; msum = msum_a; }
    else           { seq = seq_b; outp = tb; msum = msum_b; blk -= 640; }

    const int tid = threadIdx.x;
    const int tok0 = blk * TM;
    const int sample = tok0 / TOK_PER_SAMPLE;
    const int fx = tid & 31;   // feature group: h = fx*4 .. fx*4+3
    const int ty = tid >> 5;   // token group: tokens ty*8 .. ty*8+7

    if (tid < H) msum_s[tid] = 0.f;

    float acc[8][4];
#pragma unroll
    for (int r = 0; r < 8; ++r)
#pragma unroll
        for (int c = 0; c < 4; ++c) acc[r][c] = 0.f;

    for (int k0 = 0; k0 < K_FEAT; k0 += KC) {
        // Stage A tile: 64 tokens x KC(=60) floats, as float4 (60/4 = 15 per token)
        for (int i4 = tid; i4 < TM * (KC / 4); i4 += 256) {
            int t = i4 / (KC / 4);
            int k4 = i4 - t * (KC / 4);
            float4 v = *(const float4*)&seq[(size_t)(tok0 + t) * K_FEAT + k0 + k4 * 4];
            *(float4*)&A_s[t * KC + k4 * 4] = v;
        }
        // Stage W tile: KC x 128 floats, as float4 (32 float4 per k-row)
        for (int i4 = tid; i4 < KC * (H / 4); i4 += 256) {
            int k = i4 >> 5;
            int h4 = i4 & 31;
            float4 v = *(const float4*)&W[(size_t)(k0 + k) * H + h4 * 4];
            *(float4*)&W_s[k * H + h4 * 4] = v;
        }
        __syncthreads();

#pragma unroll 4
        for (int k = 0; k < KC; ++k) {
            float4 w = *(const float4*)&W_s[k * H + fx * 4];
            float a[8];
#pragma unroll
            for (int r = 0; r < 8; ++r) a[r] = A_s[(ty * 8 + r) * KC + k];
#pragma unroll
            for (int r = 0; r < 8; ++r) {
                acc[r][0] = fmaf(a[r], w.x, acc[r][0]);
                acc[r][1] = fmaf(a[r], w.y, acc[r][1]);
                acc[r][2] = fmaf(a[r], w.z, acc[r][2]);
                acc[r][3] = fmaf(a[r], w.w, acc[r][3]);
            }
        }
        __syncthreads();
    }

    // Epilogue: + bias, ReLU, store; accumulate per-feature sums for the mean
    float4 bb = *(const float4*)&bias[fx * 4];
    float fsum[4] = {0.f, 0.f, 0.f, 0.f};
#pragma unroll
    for (int r = 0; r < 8; ++r) {
        int tok = tok0 + ty * 8 + r;
        float4 v;
        v.x = fmaxf(acc[r][0] + bb.x, 0.f);
        v.y = fmaxf(acc[r][1] + bb.y, 0.f);
        v.z = fmaxf(acc[r][2] + bb.z, 0.f);
        v.w = fmaxf(acc[r][3] + bb.w, 0.f);
        fsum[0] += v.x; fsum[1] += v.y; fsum[2] += v.z; fsum[3] += v.w;
        *(float4*)&outp[(size_t)tok * H + fx * 4] = v;
    }
    // Block-local reduce (8 ty-groups share each feature), then one global atomic/feature
    atomicAdd(&msum_s[fx * 4 + 0], fsum[0]);
    atomicAdd(&msum_s[fx * 4 + 1], fsum[1]);
    atomicAdd(&msum_s[fx * 4 + 2], fsum[2]);
    atomicAdd(&msum_s[fx * 4 + 3], fsum[3]);
    __syncthreads();
    if (tid < H) atomicAdd(&msum[sample * H + tid], msum_s[tid]);
}

// ---------------- Kernel 2: scores -> masked softmax -> weighted sum ----------------
// grid.x = 640 (320 reviews x 2 sides); block = 256
__global__ __launch_bounds__(256) void attn_kernel(
    const float* __restrict__ ta, const float* __restrict__ tb,
    const int* __restrict__ mask_a, const int* __restrict__ mask_b,
    const float* __restrict__ msum_a, const float* __restrict__ msum_b,
    float* __restrict__ out)
{
    int n = blockIdx.x;
    int side = 0;
    if (n >= NREV) { side = 1; n -= NREV; }

    const float* t = side ? tb : ta;
    const int* mask = side ? mask_b : mask_a;
    const float* mean_o = side ? msum_a : msum_b;  // raw sums of the OTHER side
    float* out_vec = out + (side ? NREV * H : 0);              // a_out / b_out
    float* out_w = out + 2 * NREV * H + (side ? NREV * H : 0); // atob_w / btoa_w

    int sample = n / 10;
    int tid = threadIdx.x;

    __shared__ float tile[128 * 129];  // pad +1: row-dot conflict-free
    __shared__ float mean_s[128];
    __shared__ float w_s[128];
    __shared__ float red[4];
    __shared__ float red2[128];

    const float* rowbase = t + (size_t)n * 128 * H;
    for (int i = tid; i < 128 * H; i += 256) {
        int r = i >> 7, d = i & 127;
        tile[r * 129 + d] = rowbase[i];
    }
    if (tid < 128) mean_s[tid] = mean_o[sample * H + tid] * (1.0f / (float)TOK_PER_SAMPLE);
    __syncthreads();

    // score_l = dot(row l, mean_other); waves 2,3 carry -inf (contribute 0 after exp)
    float logit = -1e9f;
    if (tid < 128) {
        int l = tid;
        float s = 0.f;
        const float* myrow = &tile[l * 129];
#pragma unroll 8
        for (int j = 0; j < 128; ++j) s = fmaf(myrow[j], mean_s[j], s);
        int mv = mask[n * 128 + l];
        logit = (mv > 0) ? s : -1e9f;
    }

    // block max over 4 waves
    float mx = logit;
    for (int off = 32; off > 0; off >>= 1) mx = fmaxf(mx, __shfl_xor(mx, off));
    if ((tid & 63) == 0) red[tid >> 6] = mx;
    __syncthreads();
    mx = fmaxf(fmaxf(red[0], red[1]), fmaxf(red[2], red[3]));
    __syncthreads();  // red reused

    float e = __expf(logit - mx);  // masked / idle lanes: exp(very negative) -> 0
    float ssum = e;
    for (int off = 32; off > 0; off >>= 1) ssum += __shfl_xor(ssum, off);
    if ((tid & 63) == 0) red[tid >> 6] = ssum;
    __syncthreads();
    ssum = red[0] + red[1] + red[2] + red[3];

    float w = e / ssum;
    if (tid < 128) {
        w_s[tid] = w;
        out_w[n * 128 + tid] = w;
    }
    __syncthreads();

    // out[d] = sum_l w_l * tile[l][d]; 256 threads: (d = tid&127, half of l range each)
    int d = tid & 127;
    int hf = tid >> 7;
    float o = 0.f;
#pragma unroll 8
    for (int ll = hf * 64; ll < hf * 64 + 64; ++ll)
        o = fmaf(w_s[ll], tile[ll * 129 + d], o);
    if (hf == 0) red2[d] = o;
    __syncthreads();
    if (hf == 1) out_vec[n * 128 + d] = red2[d] + o;
}

// ---------------- Launch ----------------
extern "C" void kernel_launch(void* const* d_in, const int* in_sizes, int n_in,
                              void* d_out, int out_size, void* d_ws, size_t ws_size,
                              hipStream_t stream)
{
    const float* seq_a = (const float*)d_in[0];
    const float* seq_b = (const float*)d_in[1];
    const int* mask_a = (const int*)d_in[2];
    const int* mask_b = (const int*)d_in[3];
    const float* W = (const float*)d_in[4];
    const float* bias = (const float*)d_in[5];
    float* out = (float*)d_out;

    float* ws = (float*)d_ws;
    float* ta = ws;                          // 40960*128
    float* tb = ta + (size_t)NTOK * H;       // 40960*128
    float* msum_a = tb + (size_t)NTOK * H;   // 32*128 raw sums
    float* msum_b = msum_a + 32 * H;         // 32*128

    zero_kernel<<<(2 * 32 * H + 255) / 256, 256, 0, stream>>>(msum_a, 2 * 32 * H);
    fc_relu_kernel<<<1280, 256, 0, stream>>>(seq_a, seq_b, W, bias, ta, tb, msum_a, msum_b);
    attn_kernel<<<640, 256, 0, stream>>>(ta, tb, mask_a, mask_b, msum_a, msum_b, out);
}